// Round 17
// baseline (154.145 us; speedup 1.0000x reference)
//
#include <hip/hip_runtime.h>

// LSTM: HIDDEN=128, SEQ=7, BATCH=65536. fp32 in/out.
//
// R24: persistent blocks on R22 (92.8us best; R23's distributed pred
// regressed to 97.2 -> reverted, incl. setprio).
//  * grid=512 = exactly 2 blocks/CU; each block loops over 4 chunks of
//    BT=32 rows (rowbase = blockIdx*128 + c*32). bw (128KB/block), Wo,
//    Tw/Tb loaded ONCE instead of per-generation: kills 3 redundant
//    prologues (262MB -> 65MB L2 weight traffic) + generation tails.
//  * Per chunk: c2 reset + xs init + 1 barrier (also fences prev chunk's
//    tail Ah[1] read from this chunk's t=0 Ah[1] write).
//  * t-loop body byte-identical to R22: concentrated pred (waves 0-1,
//    direct global store), packed pk-fma acc-init, packed exp2
//    fused-reciprocal epilogue, cvt_pkrtz h-staging, 1 barrier/t.

#define SEQ 7
#define BT 32

typedef _Float16 half8 __attribute__((ext_vector_type(8)));
typedef __fp16 fp16x2 __attribute__((ext_vector_type(2)));
typedef float floatx4 __attribute__((ext_vector_type(4)));
typedef float floatx2 __attribute__((ext_vector_type(2)));

__device__ __forceinline__ floatx4 mfma16(half8 a, half8 b, floatx4 c) {
  return __builtin_amdgcn_mfma_f32_16x16x32_f16(a, b, c, 0, 0, 0);
}

#define LOG2E 1.4426950408889634f
#define K2 2.885390081777927f  // 2*log2e

__device__ __forceinline__ floatx2 pexp2m(floatx2 v) {
  floatx2 r;
  r.x = __builtin_amdgcn_exp2f(-v.x);
  r.y = __builtin_amdgcn_exp2f(-v.y);
  return r;
}
__device__ __forceinline__ floatx2 prcp(floatx2 v) {
  floatx2 r;
  r.x = __builtin_amdgcn_rcpf(v.x);
  r.y = __builtin_amdgcn_rcpf(v.y);
  return r;
}

// Pack W_hh [512][128] fp32 -> B-fragment-major fp16, prescaled (idx<65536):
//   Bp[((nt*4+kk)*64 + lane)*8 + jj] = S(g) * Whh[j][k]
//   nt=g*8+w, j=g*128+w*16+col, k=32kk+8quad+jj.
// idx in [65536, 69632): W_out hi/lo fragments, col-0-only 16-col tile.
__global__ void pack_kernel(const float* __restrict__ Whh,
                            const float* __restrict__ Wout,
                            _Float16* __restrict__ Bp) {
  int idx = blockIdx.x * 256 + threadIdx.x;  // 0..69631
  if (idx < 65536) {
    int jj = idx & 7;
    int lane = (idx >> 3) & 63;
    int kk = (idx >> 9) & 3;
    int nt = idx >> 11;  // 0..31
    int g = nt >> 3, w = nt & 7;
    int col = lane & 15, quad = lane >> 4;
    int j = g * 128 + w * 16 + col;
    int k = 32 * kk + 8 * quad + jj;
    float S = (g == 2) ? K2 : LOG2E;
    Bp[idx] = (_Float16)(S * Whh[j * 128 + k]);
  } else {
    int pos = idx - 65536;  // 0..4095
    int hl = pos >> 11;     // 0 = hi, 1 = lo
    int e = pos & 2047;
    int jj = e & 7;
    int lane = (e >> 3) & 63;
    int kk = e >> 9;
    int col = lane & 15, quad = lane >> 4;
    int k = 32 * kk + 8 * quad + jj;
    float wv = Wout[k];
    _Float16 hi = (_Float16)wv;
    _Float16 v = hl ? (_Float16)(wv - (float)hi) : hi;
    Bp[idx] = (col == 0) ? v : (_Float16)0.0f;
  }
}

__launch_bounds__(512, 4)
__global__ void lstm_kernel(const float* __restrict__ x,
                            const float* __restrict__ x0,
                            const float* __restrict__ Wih,
                            const float* __restrict__ bih,
                            const float* __restrict__ bhh,
                            const float* __restrict__ boutp,
                            const _Float16* __restrict__ Bp,
                            float* __restrict__ out) {
  // h staged fp16, double-buffered, 272B row stride (+8 pad).
  __shared__ _Float16 Ah[2][BT][136];  // 17,408 B
  __shared__ float xs[2][BT];          // 256 B
  __shared__ _Float16 Wo[4096];        // 8 KB W_out hi/lo B-fragments
  __shared__ floatx4 Tw[8][16];        // 2 KB prescaled wih per (w,col)
  __shared__ floatx4 Tb[8][16];        // 2 KB prescaled bias per (w,col)

  const int tid = threadIdx.x;
  const int w = tid >> 6;  // wave 0..7: owns hcols [16w, 16w+16)
  const int lane = tid & 63;
  const int col = lane & 15;
  const int quad = lane >> 4;

  // ---- persistent prologue (once per block) ----
  // stage W_out fragments into LDS (512 x 16B)
  ((half8*)Wo)[tid] = ((const half8*)(Bp + 65536))[tid];

  // build per-(w,col) prescaled wih/bias tables (16B entries)
  if (tid < 128) {
    int tw = tid >> 4, tc = tid & 15;
    float* pw = (float*)&Tw[tw][tc];
    float* pb = (float*)&Tb[tw][tc];
#pragma unroll
    for (int g = 0; g < 4; ++g) {
      int j = g * 128 + tw * 16 + tc;
      float S = (g == 2) ? K2 : LOG2E;
      pw[g] = S * Wih[j];
      pb[g] = S * (bih[j] + bhh[j]);
    }
  }

  // Gate-GEMM weight fragments: 64 regs (AGPR), loaded ONCE for all chunks.
  half8 bw[4][4];
#pragma unroll
  for (int g = 0; g < 4; ++g)
#pragma unroll
    for (int kk = 0; kk < 4; ++kk)
      bw[g][kk] =
          *(const half8*)(Bp + (((g * 8 + w) * 4 + kk) * 64 + lane) * 8);

  const float bout = boutp[0];

  // ---- chunk loop: 4 x BT=32 rows per block ----
#pragma unroll 1
  for (int c = 0; c < 4; ++c) {
    const int rowbase = blockIdx.x * 128 + c * 32;

    // Scaled cell state c~ = 2log2e*c, reset per chunk.
    floatx2 c2[2][2];
#pragma unroll
    for (int mt = 0; mt < 2; ++mt)
#pragma unroll
      for (int p = 0; p < 2; ++p) c2[mt][p] = (floatx2){0.f, 0.f};

    if (tid < BT) xs[0][tid] = x0[rowbase + tid];  // t=0 consumes x0
    // barrier: xs ready; also fences prev chunk's tail Ah[1] read from
    // this chunk's t=0 Ah[1] write (and chunk 0: Wo/Tw/Tb staging).
    __syncthreads();

#pragma unroll 1
    for (int t = 0; t < SEQ; ++t) {
      const int cur = t & 1, nxt = cur ^ 1;

      // prefetch input for t+1 (consumes x[:, t])
      if (t + 1 < SEQ && tid < BT) {
        xs[nxt][tid] = x[(size_t)(rowbase + tid) * 7 + t];
      }

#pragma unroll
      for (int mt = 0; mt < 2; ++mt) {
        // x for the 4 rows (mt*16 + quad*4 + r) this lane covers.
        floatx4 xq = *(const floatx4*)&xs[cur][mt * 16 + quad * 4];

        // wih/bias from LDS, volatile so they stay transient.
        floatx4 wihv = *(volatile const floatx4*)&Tw[w][col];
        floatx4 biasv = *(volatile const floatx4*)&Tb[w][col];

        // acc init = x*W_ih + bias, PACKED (v_pk_fma_f32).
        floatx4 acc[4];
#pragma unroll
        for (int g = 0; g < 4; ++g) acc[g] = xq * wihv[g] + biasv[g];

        const bool dopred = (w < 2) && (mt == w);  // wave-uniform

        if (t != 0) {  // h(0)=0: skip GEMM at t=0
          floatx4 ap = (floatx4){0.f, 0.f, 0.f, 0.f};  // pred(t-1) partial
#pragma unroll
          for (int kk = 0; kk < 4; ++kk) {
            half8 ah =
                *(const half8*)&Ah[cur][mt * 16 + col][kk * 32 + quad * 8];
#pragma unroll
            for (int g = 0; g < 4; ++g)
              acc[g] = mfma16(ah, bw[g][kk], acc[g]);
            if (dopred) {
              half8 bo0 = *(const half8*)&Wo[(kk * 64 + lane) * 8];
              half8 bo1 = *(const half8*)&Wo[2048 + (kk * 64 + lane) * 8];
              ap = mfma16(ah, bo0, ap);
              ap = mfma16(ah, bo1, ap);
            }
          }
          if (dopred && col == 0) {
#pragma unroll
            for (int r = 0; r < 4; ++r)
              out[(size_t)(rowbase + mt * 16 + quad * 4 + r) * 7 + (t - 1)] =
                  ap[r] + bout;
          }
        }

        // Fused-reciprocal cell update, PACKED pairs (r01, r23).
        const floatx2 one2 = {1.0f, 1.0f};
        const floatx2 k22 = {K2, K2};
#pragma unroll
        for (int p = 0; p < 2; ++p) {
          floatx2 Gi, Gf, Gg, Go;
          Gi.x = acc[0][2 * p];
          Gi.y = acc[0][2 * p + 1];
          Gf.x = acc[1][2 * p];
          Gf.y = acc[1][2 * p + 1];
          Gg.x = acc[2][2 * p];
          Gg.y = acc[2][2 * p + 1];
          Go.x = acc[3][2 * p];
          Go.y = acc[3][2 * p + 1];
          floatx2 A = pexp2m(Gi);
          floatx2 Bv = pexp2m(Gf);
          floatx2 Cv = pexp2m(Gg);
          floatx2 Dv = pexp2m(Go);
          floatx2 a1 = A + one2;
          floatx2 b1 = Bv + one2;
          floatx2 c1 = Cv + one2;
          floatx2 ac = a1 * c1;
          floatx2 t1 = k22 - Cv * k22;
          floatx2 num = c2[mt][p] * ac + t1 * b1;
          floatx2 den = ac * b1;
          floatx2 cn = num * prcp(den);
          c2[mt][p] = cn;
          floatx2 E = pexp2m(cn);
          floatx2 de = (Dv + one2) * (E + one2);
          floatx2 hn = (one2 - E) * prcp(de);

          // stage h_new: one packed cvt (RTZ), two b16 stores.
          fp16x2 hp = __builtin_amdgcn_cvt_pkrtz(hn.x, hn.y);
          const int rbase = mt * 16 + quad * 4 + 2 * p;
          Ah[nxt][rbase][w * 16 + col] = (_Float16)hp.x;
          Ah[nxt][rbase + 1][w * 16 + col] = (_Float16)hp.y;
        }
      }
      // single barrier per t: h staging + xs prefetch complete
      __syncthreads();
    }

    // tail: pred(6) from h(7) staged in Ah[1] (written at t=6)
    if (w < 2) {
      const int mt = w;
      floatx4 ap = (floatx4){0.f, 0.f, 0.f, 0.f};
#pragma unroll
      for (int kk = 0; kk < 4; ++kk) {
        half8 ah = *(const half8*)&Ah[1][mt * 16 + col][kk * 32 + quad * 8];
        half8 bo0 = *(const half8*)&Wo[(kk * 64 + lane) * 8];
        half8 bo1 = *(const half8*)&Wo[2048 + (kk * 64 + lane) * 8];
        ap = mfma16(ah, bo0, ap);
        ap = mfma16(ah, bo1, ap);
      }
      if (col == 0) {
#pragma unroll
        for (int r = 0; r < 4; ++r)
          out[(size_t)(rowbase + mt * 16 + quad * 4 + r) * 7 + 6] =
              ap[r] + bout;
      }
    }
  }
}

extern "C" void kernel_launch(void* const* d_in, const int* in_sizes, int n_in,
                              void* d_out, int out_size, void* d_ws,
                              size_t ws_size, hipStream_t stream) {
  const float* x = (const float*)d_in[0];
  const float* x0 = (const float*)d_in[1];
  const float* Wih = (const float*)d_in[2];
  const float* Whh = (const float*)d_in[3];
  const float* bih = (const float*)d_in[4];
  const float* bhh = (const float*)d_in[5];
  const float* Wout = (const float*)d_in[6];
  const float* bout = (const float*)d_in[7];
  float* out = (float*)d_out;
  _Float16* Bp = (_Float16*)d_ws;  // 136 KB packed weights + wout frags

  pack_kernel<<<272, 256, 0, stream>>>(Whh, Wout, Bp);
  lstm_kernel<<<512, 512, 0, stream>>>(x, x0, Wih, bih, bhh, bout, Bp, out);
}

// Round 18
// 144.942 us; speedup vs baseline: 1.0635x; 1.0635x over previous
//
#include <hip/hip_runtime.h>

// LSTM: HIDDEN=128, SEQ=7, BATCH=65536. fp32 in/out.
//
// FINAL (= R22, the measured best at 92.8us). Session ladder:
// 196 -> 102 (R12 weight-stationary, spill-free (512,2))
//     -> 94.4 (R17 cap-fit (512,4): 2 blocks/CU, 16 waves/CU)
//     -> 92.8 (R22 packed pk-fma acc-init + cvt_pkrtz staging).
// Regressions measured and reverted: distributed pred (R23, 97.2),
// persistent blocks (R24, 100.9 — chunk-loop pressure spills at the
// zero-slack 128-reg cap), DPP write pairing + in-loop global x (R19),
// BT=32-alone (R16), LDS-conflict fixes (R18/R20, conflicts proven
// not wall-coupled).
// Structure: 8 waves x 16-hcol slices; W_hh prescaled (log2e / 2log2e)
// fp16 B-frags AGPR-stationary (64 regs, loaded once); bias + x*W_ih
// folded into MFMA C-init via LDS tables; exp2-form fused-reciprocal
// cell math (5 exp2 + 2 rcp per element, packed f32 pairs); h staged
// fp16 in dbuf LDS (+8 pad); pred = GEMM side column (waves 0-1, W_out
// hi+lo fp16 frags from LDS); 1 barrier/t.

#define SEQ 7
#define BT 32

typedef _Float16 half8 __attribute__((ext_vector_type(8)));
typedef __fp16 fp16x2 __attribute__((ext_vector_type(2)));
typedef float floatx4 __attribute__((ext_vector_type(4)));
typedef float floatx2 __attribute__((ext_vector_type(2)));

__device__ __forceinline__ floatx4 mfma16(half8 a, half8 b, floatx4 c) {
  return __builtin_amdgcn_mfma_f32_16x16x32_f16(a, b, c, 0, 0, 0);
}

#define LOG2E 1.4426950408889634f
#define K2 2.885390081777927f  // 2*log2e

__device__ __forceinline__ floatx2 pexp2m(floatx2 v) {
  floatx2 r;
  r.x = __builtin_amdgcn_exp2f(-v.x);
  r.y = __builtin_amdgcn_exp2f(-v.y);
  return r;
}
__device__ __forceinline__ floatx2 prcp(floatx2 v) {
  floatx2 r;
  r.x = __builtin_amdgcn_rcpf(v.x);
  r.y = __builtin_amdgcn_rcpf(v.y);
  return r;
}

// Pack W_hh [512][128] fp32 -> B-fragment-major fp16, prescaled (idx<65536):
//   Bp[((nt*4+kk)*64 + lane)*8 + jj] = S(g) * Whh[j][k]
//   nt=g*8+w, j=g*128+w*16+col, k=32kk+8quad+jj.
// idx in [65536, 69632): W_out hi/lo fragments, col-0-only 16-col tile.
__global__ void pack_kernel(const float* __restrict__ Whh,
                            const float* __restrict__ Wout,
                            _Float16* __restrict__ Bp) {
  int idx = blockIdx.x * 256 + threadIdx.x;  // 0..69631
  if (idx < 65536) {
    int jj = idx & 7;
    int lane = (idx >> 3) & 63;
    int kk = (idx >> 9) & 3;
    int nt = idx >> 11;  // 0..31
    int g = nt >> 3, w = nt & 7;
    int col = lane & 15, quad = lane >> 4;
    int j = g * 128 + w * 16 + col;
    int k = 32 * kk + 8 * quad + jj;
    float S = (g == 2) ? K2 : LOG2E;
    Bp[idx] = (_Float16)(S * Whh[j * 128 + k]);
  } else {
    int pos = idx - 65536;  // 0..4095
    int hl = pos >> 11;     // 0 = hi, 1 = lo
    int e = pos & 2047;
    int jj = e & 7;
    int lane = (e >> 3) & 63;
    int kk = e >> 9;
    int col = lane & 15, quad = lane >> 4;
    int k = 32 * kk + 8 * quad + jj;
    float wv = Wout[k];
    _Float16 hi = (_Float16)wv;
    _Float16 v = hl ? (_Float16)(wv - (float)hi) : hi;
    Bp[idx] = (col == 0) ? v : (_Float16)0.0f;
  }
}

__launch_bounds__(512, 4)
__global__ void lstm_kernel(const float* __restrict__ x,
                            const float* __restrict__ x0,
                            const float* __restrict__ Wih,
                            const float* __restrict__ bih,
                            const float* __restrict__ bhh,
                            const float* __restrict__ boutp,
                            const _Float16* __restrict__ Bp,
                            float* __restrict__ out) {
  // h staged fp16, double-buffered, 272B row stride (+8 pad).
  __shared__ _Float16 Ah[2][BT][136];  // 17,408 B
  __shared__ float xs[2][BT];          // 256 B
  __shared__ _Float16 Wo[4096];        // 8 KB W_out hi/lo B-fragments
  __shared__ floatx4 Tw[8][16];        // 2 KB prescaled wih per (w,col)
  __shared__ floatx4 Tb[8][16];        // 2 KB prescaled bias per (w,col)

  const int tid = threadIdx.x;
  const int w = tid >> 6;  // wave 0..7: owns hcols [16w, 16w+16)
  const int lane = tid & 63;
  const int col = lane & 15;
  const int quad = lane >> 4;
  const int rowbase = blockIdx.x * BT;

  // stage W_out fragments into LDS (512 x 16B)
  ((half8*)Wo)[tid] = ((const half8*)(Bp + 65536))[tid];

  // build per-(w,col) prescaled wih/bias tables (16B entries)
  if (tid < 128) {
    int tw = tid >> 4, tc = tid & 15;
    float* pw = (float*)&Tw[tw][tc];
    float* pb = (float*)&Tb[tw][tc];
#pragma unroll
    for (int g = 0; g < 4; ++g) {
      int j = g * 128 + tw * 16 + tc;
      float S = (g == 2) ? K2 : LOG2E;
      pw[g] = S * Wih[j];
      pb[g] = S * (bih[j] + bhh[j]);
    }
  }

  // Gate-GEMM weight fragments: 64 regs (AGPR), loaded once.
  half8 bw[4][4];
#pragma unroll
  for (int g = 0; g < 4; ++g)
#pragma unroll
    for (int kk = 0; kk < 4; ++kk)
      bw[g][kk] =
          *(const half8*)(Bp + (((g * 8 + w) * 4 + kk) * 64 + lane) * 8);

  const float bout = boutp[0];

  // Scaled cell state c~ = 2log2e*c, pair-major float2 -> 8 registers.
  floatx2 c2[2][2];
#pragma unroll
  for (int mt = 0; mt < 2; ++mt)
#pragma unroll
    for (int p = 0; p < 2; ++p) c2[mt][p] = (floatx2){0.f, 0.f};

  if (tid < BT) xs[0][tid] = x0[rowbase + tid];  // t=0 consumes x0
  __syncthreads();

#pragma unroll 1
  for (int t = 0; t < SEQ; ++t) {
    const int cur = t & 1, nxt = cur ^ 1;

    // prefetch input for t+1 (consumes x[:, t])
    if (t + 1 < SEQ && tid < BT) {
      xs[nxt][tid] = x[(size_t)(rowbase + tid) * 7 + t];
    }

#pragma unroll
    for (int mt = 0; mt < 2; ++mt) {
      // x for the 4 rows (mt*16 + quad*4 + r) this lane covers.
      floatx4 xq = *(const floatx4*)&xs[cur][mt * 16 + quad * 4];

      // wih/bias from LDS, volatile so they stay transient (no re-hoist).
      floatx4 wihv = *(volatile const floatx4*)&Tw[w][col];
      floatx4 biasv = *(volatile const floatx4*)&Tb[w][col];

      // acc init = x*W_ih + bias, PACKED (v_pk_fma_f32 w/ op_sel extract).
      floatx4 acc[4];
#pragma unroll
      for (int g = 0; g < 4; ++g) acc[g] = xq * wihv[g] + biasv[g];

      const bool dopred = (w < 2) && (mt == w);  // wave-uniform

      if (t != 0) {  // h(0)=0: skip GEMM at t=0
        floatx4 ap = (floatx4){0.f, 0.f, 0.f, 0.f};  // pred(t-1) partial
#pragma unroll
        for (int kk = 0; kk < 4; ++kk) {
          half8 ah =
              *(const half8*)&Ah[cur][mt * 16 + col][kk * 32 + quad * 8];
#pragma unroll
          for (int g = 0; g < 4; ++g) acc[g] = mfma16(ah, bw[g][kk], acc[g]);
          if (dopred) {
            half8 bo0 = *(const half8*)&Wo[(kk * 64 + lane) * 8];
            half8 bo1 = *(const half8*)&Wo[2048 + (kk * 64 + lane) * 8];
            ap = mfma16(ah, bo0, ap);
            ap = mfma16(ah, bo1, ap);
          }
        }
        if (dopred && col == 0) {
#pragma unroll
          for (int r = 0; r < 4; ++r)
            out[(size_t)(rowbase + mt * 16 + quad * 4 + r) * 7 + (t - 1)] =
                ap[r] + bout;
        }
      }

      // Fused-reciprocal cell update, PACKED pairs (r01, r23).
      const floatx2 one2 = {1.0f, 1.0f};
      const floatx2 k22 = {K2, K2};
#pragma unroll
      for (int p = 0; p < 2; ++p) {
        floatx2 Gi, Gf, Gg, Go;
        Gi.x = acc[0][2 * p];
        Gi.y = acc[0][2 * p + 1];
        Gf.x = acc[1][2 * p];
        Gf.y = acc[1][2 * p + 1];
        Gg.x = acc[2][2 * p];
        Gg.y = acc[2][2 * p + 1];
        Go.x = acc[3][2 * p];
        Go.y = acc[3][2 * p + 1];
        floatx2 A = pexp2m(Gi);
        floatx2 Bv = pexp2m(Gf);
        floatx2 Cv = pexp2m(Gg);
        floatx2 Dv = pexp2m(Go);
        floatx2 a1 = A + one2;
        floatx2 b1 = Bv + one2;
        floatx2 c1 = Cv + one2;
        floatx2 ac = a1 * c1;
        floatx2 t1 = k22 - Cv * k22;
        floatx2 num = c2[mt][p] * ac + t1 * b1;
        floatx2 den = ac * b1;
        floatx2 cn = num * prcp(den);
        c2[mt][p] = cn;
        floatx2 E = pexp2m(cn);
        floatx2 de = (Dv + one2) * (E + one2);
        floatx2 hn = (one2 - E) * prcp(de);

        // stage h_new: one packed cvt (RTZ, __fp16x2 return), two b16
        // stores (lo + d16_hi halves of the same register).
        fp16x2 hp = __builtin_amdgcn_cvt_pkrtz(hn.x, hn.y);
        const int rbase = mt * 16 + quad * 4 + 2 * p;
        Ah[nxt][rbase][w * 16 + col] = (_Float16)hp.x;
        Ah[nxt][rbase + 1][w * 16 + col] = (_Float16)hp.y;
      }
    }
    // single barrier per t: h staging + xs prefetch complete
    __syncthreads();
  }

  // tail: pred(6) from h(6) staged in Ah[SEQ&1] (= Ah[1])
  if (w < 2) {
    const int mt = w;
    floatx4 ap = (floatx4){0.f, 0.f, 0.f, 0.f};
#pragma unroll
    for (int kk = 0; kk < 4; ++kk) {
      half8 ah = *(const half8*)&Ah[1][mt * 16 + col][kk * 32 + quad * 8];
      half8 bo0 = *(const half8*)&Wo[(kk * 64 + lane) * 8];
      half8 bo1 = *(const half8*)&Wo[2048 + (kk * 64 + lane) * 8];
      ap = mfma16(ah, bo0, ap);
      ap = mfma16(ah, bo1, ap);
    }
    if (col == 0) {
#pragma unroll
      for (int r = 0; r < 4; ++r)
        out[(size_t)(rowbase + mt * 16 + quad * 4 + r) * 7 + 6] =
            ap[r] + bout;
    }
  }
}

extern "C" void kernel_launch(void* const* d_in, const int* in_sizes, int n_in,
                              void* d_out, int out_size, void* d_ws,
                              size_t ws_size, hipStream_t stream) {
  const float* x = (const float*)d_in[0];
  const float* x0 = (const float*)d_in[1];
  const float* Wih = (const float*)d_in[2];
  const float* Whh = (const float*)d_in[3];
  const float* bih = (const float*)d_in[4];
  const float* bhh = (const float*)d_in[5];
  const float* Wout = (const float*)d_in[6];
  const float* bout = (const float*)d_in[7];
  float* out = (float*)d_out;
  _Float16* Bp = (_Float16*)d_ws;  // 136 KB packed weights + wout frags

  pack_kernel<<<272, 256, 0, stream>>>(Whh, Wout, Bp);
  lstm_kernel<<<65536 / BT, 512, 0, stream>>>(x, x0, Wih, bih, bhh, bout, Bp,
                                              out);
}